// Round 16
// baseline (275.471 us; speedup 1.0000x reference)
//
#include <hip/hip_runtime.h>
#include <math.h>

#define Bb 2
#define Ss 128
#define Hh 768
#define Cc 5
#define Mm 256       // Bb*Ss
#define NEGV -1024.0f
#define SCALE 2.8853900817779268f   // 2/ln(2): stored pre-scaled so exp2(hp')*exp2(ha') = e^{2x}

// haTb: bf16 [b][c][h8][a][h&7], h8=h>>3 in [0,96)
#define PT 2
#define NPC 640               // (pt,c) softmax-row groups
#define NBLK2 1280            // NPC * 2 h-halves = 5 blocks/CU exactly

typedef __attribute__((ext_vector_type(8))) short bf16x8;
typedef __attribute__((ext_vector_type(4))) float f32x4;
typedef unsigned short ushort;

__device__ __forceinline__ unsigned pack_hi16(float hi, float lo) {
    return (__float_as_uint(hi) & 0xFFFF0000u) | (__float_as_uint(lo) >> 16);
}
__device__ __forceinline__ bf16x8 pack_bf16x8(float4 lo, float4 hi) {
    union { bf16x8 v; unsigned u[4]; } r;
    r.u[0] = pack_hi16(lo.y, lo.x);
    r.u[1] = pack_hi16(lo.w, lo.z);
    r.u[2] = pack_hi16(hi.y, hi.x);
    r.u[3] = pack_hi16(hi.w, hi.z);
    return r.v;
}

#define SB __builtin_amdgcn_sched_barrier(0);

// ---------------- Kernel 1: LDS-staged bf16 MFMA GEMM, 64x32 tiles (unchanged from R15) ----------------
__global__ __launch_bounds__(256)
void gemm_mfma(const float* __restrict__ X,
               const float* __restrict__ Wprd,
               const float* __restrict__ Warg,
               const float* __restrict__ bprd,
               const float* __restrict__ barg,
               float* __restrict__ hp_out,
               ushort* __restrict__ haTb,
               float* __restrict__ accum,
               unsigned* __restrict__ cnt)
{
    __shared__ __align__(16) ushort Asb[64][40];
    __shared__ __align__(16) ushort Bsb[32][40];

    if (blockIdx.x == 0 && blockIdx.y == 0) {
        for (int i = threadIdx.x; i < NPC; i += 256) cnt[i] = 0u;
        if (threadIdx.x == 0) {
            accum[0] = 0.f; accum[1] = 0.f;
            ((unsigned*)accum)[2] = 0u;
        }
    }
    const int bm   = blockIdx.x;          // 0..3   (64 rows)
    const int bn   = blockIdx.y;          // 0..143 (32 cols)
    const int tid  = threadIdx.x;
    const int wave = tid >> 6;
    const int lane = tid & 63;
    const int l16  = lane & 15;
    const int quad = lane >> 4;

    const float* Wsrc; const float* bsrc;
    const int nb = bn * 32;
    if (nb < Hh) { Wsrc = Wprd + (size_t)nb * Hh;        bsrc = bprd + nb; }
    else         { Wsrc = Warg + (size_t)(nb - Hh) * Hh; bsrc = barg + (nb - Hh); }

    const int srow = tid >> 2;
    const int sko  = (tid & 3) * 8;
    const float* gA = X + (size_t)(bm * 64 + srow) * Hh + sko;
    const float* gB = Wsrc + (size_t)(tid >> 2) * Hh + sko;   // valid for tid<128

    float4 pa0 = *(const float4*)(gA);
    float4 pa1 = *(const float4*)(gA + 4);
    float4 pb0, pb1;
    if (tid < 128) { pb0 = *(const float4*)(gB); pb1 = *(const float4*)(gB + 4); }

    f32x4 acc0 = {0.f,0.f,0.f,0.f}, acc1 = {0.f,0.f,0.f,0.f};

    for (int k0 = 0; k0 < Hh; k0 += 32) {
        *(bf16x8*)&Asb[srow][sko] = pack_bf16x8(pa0, pa1);
        if (tid < 128) *(bf16x8*)&Bsb[tid >> 2][sko] = pack_bf16x8(pb0, pb1);
        __syncthreads();
        const int kn = k0 + 32;
        if (kn < Hh) {
            pa0 = *(const float4*)(gA + kn);
            pa1 = *(const float4*)(gA + kn + 4);
            if (tid < 128) { pb0 = *(const float4*)(gB + kn); pb1 = *(const float4*)(gB + kn + 4); }
        }
        bf16x8 af = *(const bf16x8*)&Asb[wave * 16 + l16][quad * 8];
        bf16x8 b0 = *(const bf16x8*)&Bsb[l16][quad * 8];
        bf16x8 b1 = *(const bf16x8*)&Bsb[16 + l16][quad * 8];
        acc0 = __builtin_amdgcn_mfma_f32_16x16x32_bf16(af, b0, acc0, 0, 0, 0);
        acc1 = __builtin_amdgcn_mfma_f32_16x16x32_bf16(af, b1, acc1, 0, 0, 0);
        __syncthreads();
    }

    const float sb0 = SCALE * bsrc[l16];
    const float sb1 = SCALE * bsrc[16 + l16];
    const int row = bm * 64 + wave * 16 + quad * 4;

    if (nb < Hh) {
        #pragma unroll
        for (int r = 0; r < 4; ++r) {
            const int mm = row + r;
            hp_out[(size_t)mm * Hh + nb + l16]      = SCALE * acc0[r] + sb0;
            hp_out[(size_t)mm * Hh + nb + 16 + l16] = SCALE * acc1[r] + sb1;
        }
    } else {
        const int q  = nb - Hh;
        const int cU = q / Hh;
        const int h0 = q % Hh;
        const int hA = h0 + l16;
        const int hB = h0 + 16 + l16;
        const size_t offA = (size_t)(hA >> 3) * 1024 + (hA & 7);
        const size_t offB = (size_t)(hB >> 3) * 1024 + (hB & 7);
        #pragma unroll
        for (int r = 0; r < 4; ++r) {
            const int mm = row + r;
            const int bI = mm >> 7, aI = mm & 127;
            const size_t base = ((size_t)(bI * Cc + cU) * 96) * 1024 + (size_t)aI * 8;
            const float v0 = SCALE * acc0[r] + sb0;
            const float v1 = SCALE * acc1[r] + sb1;
            haTb[base + offA] = (ushort)(__float_as_uint(v0) >> 16);
            haTb[base + offB] = (ushort)(__float_as_uint(v1) >> 16);
        }
    }
}

// ---------------- Kernel 2: biaffine, grid 1280 = (pt,c,h2), factorized exp2 ----------------
// Block 256: tid = hsub*128 + a; thread streams 24 uint4 (192 h) of its (h2,hsub) range, PT=2.
// tanh term: w * rcp(Ep*Ea + 1), Ep = exp2(hp') from LDS, Ea = exp2(ha') shared across p.
// Partial P = wsum_half - 2*sum written to scratch; second-arriving h2 block finishes the row.
#define LOADG4(R, g) \
    R##0 = hap4[((g)*4+0)*128]; R##1 = hap4[((g)*4+1)*128]; \
    R##2 = hap4[((g)*4+2)*128]; R##3 = hap4[((g)*4+3)*128];

#define C1(u, hx) { \
    const float e0 = __builtin_amdgcn_exp2f(__uint_as_float((u).x << 16)); \
    const float e1 = __builtin_amdgcn_exp2f(__uint_as_float((u).x & 0xFFFF0000u)); \
    const float e2 = __builtin_amdgcn_exp2f(__uint_as_float((u).y << 16)); \
    const float e3 = __builtin_amdgcn_exp2f(__uint_as_float((u).y & 0xFFFF0000u)); \
    const float e4 = __builtin_amdgcn_exp2f(__uint_as_float((u).z << 16)); \
    const float e5 = __builtin_amdgcn_exp2f(__uint_as_float((u).z & 0xFFFF0000u)); \
    const float e6 = __builtin_amdgcn_exp2f(__uint_as_float((u).w << 16)); \
    const float e7 = __builtin_amdgcn_exp2f(__uint_as_float((u).w & 0xFFFF0000u)); \
    const float4 wA  = *(const float4*)(wc_s + (hx)); \
    const float4 wB  = *(const float4*)(wc_s + (hx) + 4); \
    const float4 p0A = *(const float4*)(&Eps[0][hx]); \
    const float4 p0B = *(const float4*)(&Eps[0][(hx) + 4]); \
    const float4 p1A = *(const float4*)(&Eps[1][hx]); \
    const float4 p1B = *(const float4*)(&Eps[1][(hx) + 4]); \
    float r; \
    r = __builtin_amdgcn_rcpf(fmaf(p0A.x, e0, 1.0f)); ac00 = fmaf(wA.x, r, ac00); \
    r = __builtin_amdgcn_rcpf(fmaf(p0A.y, e1, 1.0f)); ac01 = fmaf(wA.y, r, ac01); \
    r = __builtin_amdgcn_rcpf(fmaf(p0A.z, e2, 1.0f)); ac00 = fmaf(wA.z, r, ac00); \
    r = __builtin_amdgcn_rcpf(fmaf(p0A.w, e3, 1.0f)); ac01 = fmaf(wA.w, r, ac01); \
    r = __builtin_amdgcn_rcpf(fmaf(p0B.x, e4, 1.0f)); ac00 = fmaf(wB.x, r, ac00); \
    r = __builtin_amdgcn_rcpf(fmaf(p0B.y, e5, 1.0f)); ac01 = fmaf(wB.y, r, ac01); \
    r = __builtin_amdgcn_rcpf(fmaf(p0B.z, e6, 1.0f)); ac00 = fmaf(wB.z, r, ac00); \
    r = __builtin_amdgcn_rcpf(fmaf(p0B.w, e7, 1.0f)); ac01 = fmaf(wB.w, r, ac01); \
    r = __builtin_amdgcn_rcpf(fmaf(p1A.x, e0, 1.0f)); ac10 = fmaf(wA.x, r, ac10); \
    r = __builtin_amdgcn_rcpf(fmaf(p1A.y, e1, 1.0f)); ac11 = fmaf(wA.y, r, ac11); \
    r = __builtin_amdgcn_rcpf(fmaf(p1A.z, e2, 1.0f)); ac10 = fmaf(wA.z, r, ac10); \
    r = __builtin_amdgcn_rcpf(fmaf(p1A.w, e3, 1.0f)); ac11 = fmaf(wA.w, r, ac11); \
    r = __builtin_amdgcn_rcpf(fmaf(p1B.x, e4, 1.0f)); ac10 = fmaf(wB.x, r, ac10); \
    r = __builtin_amdgcn_rcpf(fmaf(p1B.y, e5, 1.0f)); ac11 = fmaf(wB.y, r, ac11); \
    r = __builtin_amdgcn_rcpf(fmaf(p1B.z, e6, 1.0f)); ac10 = fmaf(wB.z, r, ac10); \
    r = __builtin_amdgcn_rcpf(fmaf(p1B.w, e7, 1.0f)); ac11 = fmaf(wB.w, r, ac11); \
}

#define CONSUMEG4(R, g) \
    C1(R##0, hbase + ((g)*4+0)*8)  C1(R##1, hbase + ((g)*4+1)*8) \
    C1(R##2, hbase + ((g)*4+2)*8)  C1(R##3, hbase + ((g)*4+3)*8)

__global__ __launch_bounds__(256, 5)
void biaffine_loss(const float* __restrict__ hp_all,
                   const ushort* __restrict__ haTb,
                   const float* __restrict__ Wout,
                   const int* __restrict__ ng,
                   const int* __restrict__ att,
                   const float* __restrict__ target,
                   float* __restrict__ out_logits,
                   float* __restrict__ accum,
                   float* __restrict__ out_loss,
                   float* __restrict__ scratch,
                   unsigned* __restrict__ cnt)
{
    __shared__ float Eps[PT][384];
    __shared__ float wc_s[384];
    __shared__ float partial[PT][Ss];
    __shared__ float redmax[PT][2];
    __shared__ float red3[PT][2][3];
    __shared__ float wsum_s;
    __shared__ int isfin_s;

    const int bx  = blockIdx.x;
    const int h2  = bx & 1;
    const int pc  = bx >> 1;            // 0..639
    const int pt  = pc / Cc;
    const int c   = pc - pt * Cc;
    const int bp0 = pt * PT;
    const int b   = bp0 >> 7;
    const int tid = threadIdx.x;
    const int a   = tid & (Ss - 1);
    const int hsub = tid >> 7;          // 0/1: sub-half (192 h each)
    const int lane = tid & 63;

    // stage Ep = exp2(hp') and wc for this h-half
    for (int i = tid; i < PT * 384; i += 256) {
        const int p = i >> 8 >> 1;      // i/384 for i<768: p = i>=384
        const int pi = (i >= 384) ? 1 : 0;
        const int hi = i - pi * 384;
        Eps[pi][hi] = __builtin_amdgcn_exp2f(hp_all[(size_t)(bp0 + pi) * Hh + h2 * 384 + hi]);
        (void)p;
    }
    for (int i = tid; i < 384; i += 256)
        wc_s[i] = Wout[(size_t)c * Hh + h2 * 384 + i];
    __syncthreads();

    if (tid < 64) {    // wave 0: half-row weight sum
        float s = 0.f;
        #pragma unroll
        for (int i = 0; i < 6; ++i) s += wc_s[tid + i * 64];
        #pragma unroll
        for (int off = 32; off; off >>= 1) s += __shfl_xor(s, off, 64);
        if (tid == 0) wsum_s = s;
    }

    // ha stream: uint4 j (8 h each); global h8 = h2*48 + hsub*24 + j
    const uint4* hap4 = (const uint4*)(haTb + ((size_t)(b * Cc + c) * 96) * 1024)
                      + (size_t)(h2 * 48 + hsub * 24) * 128 + a;
    const int hbase = hsub * 192;

    uint4 A0, A1, A2, A3;
    uint4 B0, B1, B2, B3;
    float ac00 = 0.f, ac01 = 0.f, ac10 = 0.f, ac11 = 0.f;

    LOADG4(A, 0) SB
    LOADG4(B, 1) SB  CONSUMEG4(A, 0) SB
    LOADG4(A, 2) SB  CONSUMEG4(B, 1) SB
    LOADG4(B, 3) SB  CONSUMEG4(A, 2) SB
    LOADG4(A, 4) SB  CONSUMEG4(B, 3) SB
    LOADG4(B, 5) SB  CONSUMEG4(A, 4) SB
    CONSUMEG4(B, 5)

    const float s0 = ac00 + ac01;
    const float s1 = ac10 + ac11;
    if (hsub == 1) { partial[0][a] = s0; partial[1][a] = s1; }
    __syncthreads();
    if (hsub == 0) {   // self-contained half-partial: wsum_half - 2*sum
        scratch[(((size_t)pc * 2 + h2) * PT + 0) * Ss + a] = wsum_s - 2.0f * (s0 + partial[0][a]);
        scratch[(((size_t)pc * 2 + h2) * PT + 1) * Ss + a] = wsum_s - 2.0f * (s1 + partial[1][a]);
    }
    __threadfence();   // release (per-thread, covers own stores)
    __syncthreads();
    if (tid == 0) isfin_s = (atomicAdd(&cnt[pc], 1u) == 1u);
    __syncthreads();
    if (!isfin_s) return;
    __threadfence();   // acquire before reading the other half's partials

    // ---- finisher: logits + mask + log-softmax + CE for the (pt,c) row pair ----
    float logit[PT];
    const int wv = tid >> 6;
    if (tid < Ss) {
        #pragma unroll
        for (int p = 0; p < PT; ++p) {
            int any = 0;
            if (att[b * Ss + a] > 0) {
                const int* ngp = ng + (size_t)(bp0 + p) * Cc * Ss + a;
                #pragma unroll
                for (int cc = 0; cc < Cc; ++cc) any |= ngp[cc * Ss];
            }
            const float P0 = scratch[(((size_t)pc * 2 + 0) * PT + p) * Ss + a];
            const float P1 = scratch[(((size_t)pc * 2 + 1) * PT + p) * Ss + a];
            logit[p] = P0 + P1 + (any ? 0.0f : NEGV);
            out_logits[((size_t)(bp0 + p) * Cc + c) * Ss + a] = logit[p];
            float mx = logit[p];
            #pragma unroll
            for (int off = 32; off; off >>= 1) mx = fmaxf(mx, __shfl_xor(mx, off, 64));
            if (lane == 0) redmax[p][wv] = mx;
        }
    }
    __syncthreads();

    if (tid < Ss) {
        #pragma unroll
        for (int p = 0; p < PT; ++p) {
            const float rm = fmaxf(redmax[p][0], redmax[p][1]);
            const float e  = __builtin_amdgcn_exp2f((logit[p] - rm) * 1.4426950408889634f);
            const float tg = target[((size_t)(bp0 + p) * Cc + c) * Ss + a];
            float se = e, st = tg, sx = tg * logit[p];
            #pragma unroll
            for (int off = 32; off; off >>= 1) {
                se += __shfl_xor(se, off, 64);
                st += __shfl_xor(st, off, 64);
                sx += __shfl_xor(sx, off, 64);
            }
            if (lane == 0) { red3[p][wv][0] = se; red3[p][wv][1] = st; red3[p][wv][2] = sx; }
        }
    }
    __syncthreads();

    if (tid == 0) {
        float nsum = 0.f, dsum = 0.f;
        #pragma unroll
        for (int p = 0; p < PT; ++p) {
            const float rm = fmaxf(redmax[p][0], redmax[p][1]);
            const float SE = red3[p][0][0] + red3[p][1][0];
            const float ST = red3[p][0][1] + red3[p][1][1];
            const float SX = red3[p][0][2] + red3[p][1][2];
            const float lse = rm + __builtin_amdgcn_logf(SE) * 0.6931471805599453f;
            nsum += lse * ST - SX;
            dsum += ST;
        }
        atomicAdd(&accum[0], nsum);
        atomicAdd(&accum[1], dsum);
        __threadfence();
        const unsigned old = atomicAdd((unsigned*)(accum + 2), 1u);
        if (old == (unsigned)(NPC - 1)) {
            const float n = atomicAdd(&accum[0], 0.0f);
            const float d = atomicAdd(&accum[1], 0.0f);
            out_loss[0] = n / d;
        }
    }
}

extern "C" void kernel_launch(void* const* d_in, const int* in_sizes, int n_in,
                              void* d_out, int out_size, void* d_ws, size_t ws_size,
                              hipStream_t stream) {
    const float* seq    = (const float*)d_in[0];
    const int*   att    = (const int*)  d_in[1];
    const int*   ng     = (const int*)  d_in[2];
    const float* target = (const float*)d_in[3];
    const float* Wprd   = (const float*)d_in[4];
    const float* bprd   = (const float*)d_in[5];
    const float* Warg   = (const float*)d_in[6];
    const float* barg   = (const float*)d_in[7];
    const float* Wout   = (const float*)d_in[8];

    float*    out     = (float*)d_out;
    float*    hp_out  = (float*)d_ws;                    // 196608 floats
    ushort*   haTb    = (ushort*)(hp_out + 196608);      // 983040 ushorts (491520 f)
    float*    accum   = hp_out + 196608 + 491520;        // 4 slots
    float*    scratch = accum + 4;                       // 640*2*2*128 = 327680 floats
    unsigned* cnt     = (unsigned*)(scratch + 327680);   // 640 uints

    gemm_mfma<<<dim3(4, 144), 256, 0, stream>>>(seq, Wprd, Warg, bprd, barg,
                                                hp_out, haTb, accum, cnt);
    biaffine_loss<<<dim3(NBLK2), 256, 0, stream>>>(hp_out, haTb, Wout, ng, att, target,
                                                   out + 1, accum, out, scratch, cnt);
}

// Round 17
// 134.160 us; speedup vs baseline: 2.0533x; 2.0533x over previous
//
#include <hip/hip_runtime.h>
#include <math.h>

#define Bb 2
#define Ss 128
#define Hh 768
#define Cc 5
#define Mm 256       // Bb*Ss
#define NEGV -1024.0f
#define SCALE 2.8853900817779268f   // 2/ln(2): stored pre-scaled so exp2(hp')*exp2(ha') = e^{2x}

// haTb: bf16 [b][c][h8][a][h&7], h8=h>>3 in [0,96)
#define PT 2
#define NBLK (Mm / PT * Cc)   // 640

typedef __attribute__((ext_vector_type(8))) short bf16x8;
typedef __attribute__((ext_vector_type(4))) float f32x4;
typedef unsigned short ushort;

__device__ __forceinline__ unsigned pack_hi16(float hi, float lo) {
    return (__float_as_uint(hi) & 0xFFFF0000u) | (__float_as_uint(lo) >> 16);
}
__device__ __forceinline__ bf16x8 pack_bf16x8(float4 lo, float4 hi) {
    union { bf16x8 v; unsigned u[4]; } r;
    r.u[0] = pack_hi16(lo.y, lo.x);
    r.u[1] = pack_hi16(lo.w, lo.z);
    r.u[2] = pack_hi16(hi.y, hi.x);
    r.u[3] = pack_hi16(hi.w, hi.z);
    return r.v;
}

#define SB __builtin_amdgcn_sched_barrier(0);

// ---------------- Kernel 1: LDS-staged bf16 MFMA GEMM, 64x32 tiles (R15 verbatim) ----------------
__global__ __launch_bounds__(256)
void gemm_mfma(const float* __restrict__ X,
               const float* __restrict__ Wprd,
               const float* __restrict__ Warg,
               const float* __restrict__ bprd,
               const float* __restrict__ barg,
               float* __restrict__ hp_out,
               ushort* __restrict__ haTb,
               float* __restrict__ accum)
{
    __shared__ __align__(16) ushort Asb[64][40];
    __shared__ __align__(16) ushort Bsb[32][40];

    if (blockIdx.x == 0 && blockIdx.y == 0 && threadIdx.x == 0) {
        accum[0] = 0.f; accum[1] = 0.f;
        ((unsigned*)accum)[2] = 0u;      // completion counter
    }
    const int bm   = blockIdx.x;          // 0..3   (64 rows)
    const int bn   = blockIdx.y;          // 0..143 (32 cols)
    const int tid  = threadIdx.x;
    const int wave = tid >> 6;
    const int lane = tid & 63;
    const int l16  = lane & 15;
    const int quad = lane >> 4;

    const float* Wsrc; const float* bsrc;
    const int nb = bn * 32;
    if (nb < Hh) { Wsrc = Wprd + (size_t)nb * Hh;        bsrc = bprd + nb; }
    else         { Wsrc = Warg + (size_t)(nb - Hh) * Hh; bsrc = barg + (nb - Hh); }

    const int srow = tid >> 2;
    const int sko  = (tid & 3) * 8;
    const float* gA = X + (size_t)(bm * 64 + srow) * Hh + sko;
    const float* gB = Wsrc + (size_t)(tid >> 2) * Hh + sko;   // valid for tid<128

    float4 pa0 = *(const float4*)(gA);
    float4 pa1 = *(const float4*)(gA + 4);
    float4 pb0, pb1;
    if (tid < 128) { pb0 = *(const float4*)(gB); pb1 = *(const float4*)(gB + 4); }

    f32x4 acc0 = {0.f,0.f,0.f,0.f}, acc1 = {0.f,0.f,0.f,0.f};

    for (int k0 = 0; k0 < Hh; k0 += 32) {
        *(bf16x8*)&Asb[srow][sko] = pack_bf16x8(pa0, pa1);
        if (tid < 128) *(bf16x8*)&Bsb[tid >> 2][sko] = pack_bf16x8(pb0, pb1);
        __syncthreads();
        const int kn = k0 + 32;
        if (kn < Hh) {
            pa0 = *(const float4*)(gA + kn);
            pa1 = *(const float4*)(gA + kn + 4);
            if (tid < 128) { pb0 = *(const float4*)(gB + kn); pb1 = *(const float4*)(gB + kn + 4); }
        }
        bf16x8 af = *(const bf16x8*)&Asb[wave * 16 + l16][quad * 8];
        bf16x8 b0 = *(const bf16x8*)&Bsb[l16][quad * 8];
        bf16x8 b1 = *(const bf16x8*)&Bsb[16 + l16][quad * 8];
        acc0 = __builtin_amdgcn_mfma_f32_16x16x32_bf16(af, b0, acc0, 0, 0, 0);
        acc1 = __builtin_amdgcn_mfma_f32_16x16x32_bf16(af, b1, acc1, 0, 0, 0);
        __syncthreads();
    }

    const float sb0 = SCALE * bsrc[l16];
    const float sb1 = SCALE * bsrc[16 + l16];
    const int row = bm * 64 + wave * 16 + quad * 4;

    if (nb < Hh) {   // hp: row-major fp32 [m][h]
        #pragma unroll
        for (int r = 0; r < 4; ++r) {
            const int mm = row + r;
            hp_out[(size_t)mm * Hh + nb + l16]      = SCALE * acc0[r] + sb0;
            hp_out[(size_t)mm * Hh + nb + 16 + l16] = SCALE * acc1[r] + sb1;
        }
    } else {         // ha -> haTb bf16 [b][c][h>>3][a][h&7]
        const int q  = nb - Hh;
        const int cU = q / Hh;
        const int h0 = q % Hh;
        const int hA = h0 + l16;
        const int hB = h0 + 16 + l16;
        const size_t offA = (size_t)(hA >> 3) * 1024 + (hA & 7);
        const size_t offB = (size_t)(hB >> 3) * 1024 + (hB & 7);
        #pragma unroll
        for (int r = 0; r < 4; ++r) {
            const int mm = row + r;
            const int bI = mm >> 7, aI = mm & 127;
            const size_t base = ((size_t)(bI * Cc + cU) * 96) * 1024 + (size_t)aI * 8;
            const float v0 = SCALE * acc0[r] + sb0;
            const float v1 = SCALE * acc1[r] + sb1;
            haTb[base + offA] = (ushort)(__float_as_uint(v0) >> 16);
            haTb[base + offB] = (ushort)(__float_as_uint(v1) >> 16);
        }
    }
}

// ---------------- Kernel 2: biaffine (R15 structure) + factorized exp2 ----------------
// Grid 640 = (p-tile, c), 512 thr: tid = hq*128 + a, hq 0..3; thread streams 24 uint4 (192 h).
// term = w * rcp(Ep*Ea + 1); Ep = exp2(hp') staged in LDS; Ea = exp2(ha') shared across PT=2 p.
#define LOADG4(R, g) \
    R##0 = hap4[((g)*4+0)*128]; R##1 = hap4[((g)*4+1)*128]; \
    R##2 = hap4[((g)*4+2)*128]; R##3 = hap4[((g)*4+3)*128];

#define C1(u, hx) { \
    const float e0 = __builtin_amdgcn_exp2f(__uint_as_float((u).x << 16)); \
    const float e1 = __builtin_amdgcn_exp2f(__uint_as_float((u).x & 0xFFFF0000u)); \
    const float e2 = __builtin_amdgcn_exp2f(__uint_as_float((u).y << 16)); \
    const float e3 = __builtin_amdgcn_exp2f(__uint_as_float((u).y & 0xFFFF0000u)); \
    const float e4 = __builtin_amdgcn_exp2f(__uint_as_float((u).z << 16)); \
    const float e5 = __builtin_amdgcn_exp2f(__uint_as_float((u).z & 0xFFFF0000u)); \
    const float e6 = __builtin_amdgcn_exp2f(__uint_as_float((u).w << 16)); \
    const float e7 = __builtin_amdgcn_exp2f(__uint_as_float((u).w & 0xFFFF0000u)); \
    const float4 wA  = *(const float4*)(wc_s + (hx)); \
    const float4 wB  = *(const float4*)(wc_s + (hx) + 4); \
    const float4 p0A = *(const float4*)(&Eps[0][hx]); \
    const float4 p0B = *(const float4*)(&Eps[0][(hx) + 4]); \
    const float4 p1A = *(const float4*)(&Eps[1][hx]); \
    const float4 p1B = *(const float4*)(&Eps[1][(hx) + 4]); \
    float r; \
    r = __builtin_amdgcn_rcpf(fmaf(p0A.x, e0, 1.0f)); ac00 = fmaf(wA.x, r, ac00); \
    r = __builtin_amdgcn_rcpf(fmaf(p0A.y, e1, 1.0f)); ac01 = fmaf(wA.y, r, ac01); \
    r = __builtin_amdgcn_rcpf(fmaf(p0A.z, e2, 1.0f)); ac00 = fmaf(wA.z, r, ac00); \
    r = __builtin_amdgcn_rcpf(fmaf(p0A.w, e3, 1.0f)); ac01 = fmaf(wA.w, r, ac01); \
    r = __builtin_amdgcn_rcpf(fmaf(p0B.x, e4, 1.0f)); ac00 = fmaf(wB.x, r, ac00); \
    r = __builtin_amdgcn_rcpf(fmaf(p0B.y, e5, 1.0f)); ac01 = fmaf(wB.y, r, ac01); \
    r = __builtin_amdgcn_rcpf(fmaf(p0B.z, e6, 1.0f)); ac00 = fmaf(wB.z, r, ac00); \
    r = __builtin_amdgcn_rcpf(fmaf(p0B.w, e7, 1.0f)); ac01 = fmaf(wB.w, r, ac01); \
    r = __builtin_amdgcn_rcpf(fmaf(p1A.x, e0, 1.0f)); ac10 = fmaf(wA.x, r, ac10); \
    r = __builtin_amdgcn_rcpf(fmaf(p1A.y, e1, 1.0f)); ac11 = fmaf(wA.y, r, ac11); \
    r = __builtin_amdgcn_rcpf(fmaf(p1A.z, e2, 1.0f)); ac10 = fmaf(wA.z, r, ac10); \
    r = __builtin_amdgcn_rcpf(fmaf(p1A.w, e3, 1.0f)); ac11 = fmaf(wA.w, r, ac11); \
    r = __builtin_amdgcn_rcpf(fmaf(p1B.x, e4, 1.0f)); ac10 = fmaf(wB.x, r, ac10); \
    r = __builtin_amdgcn_rcpf(fmaf(p1B.y, e5, 1.0f)); ac11 = fmaf(wB.y, r, ac11); \
    r = __builtin_amdgcn_rcpf(fmaf(p1B.z, e6, 1.0f)); ac10 = fmaf(wB.z, r, ac10); \
    r = __builtin_amdgcn_rcpf(fmaf(p1B.w, e7, 1.0f)); ac11 = fmaf(wB.w, r, ac11); \
}

#define CONSUMEG4(R, g) \
    C1(R##0, hbase + ((g)*4+0)*8)  C1(R##1, hbase + ((g)*4+1)*8) \
    C1(R##2, hbase + ((g)*4+2)*8)  C1(R##3, hbase + ((g)*4+3)*8)

__global__ __launch_bounds__(512, 6)
void biaffine_loss(const float* __restrict__ hp_all,
                   const ushort* __restrict__ haTb,
                   const float* __restrict__ Wout,
                   const int* __restrict__ ng,
                   const int* __restrict__ att,
                   const float* __restrict__ target,
                   float* __restrict__ out_logits,
                   float* __restrict__ accum,
                   float* __restrict__ out_loss)
{
    __shared__ float Eps[PT][Hh];
    __shared__ float wc_s[Hh];
    __shared__ float partial[PT][3][Ss];
    __shared__ float maskneg[PT][Ss];
    __shared__ float redmax[PT][2];
    __shared__ float red3[PT][2][3];
    __shared__ float swr_s;

    const int pt  = blockIdx.x / Cc;     // 0..127
    const int c   = blockIdx.x - pt * Cc;
    const int bp0 = pt * PT;
    const int b   = bp0 >> 7;
    const int tid = threadIdx.x;
    const int a   = tid & (Ss - 1);
    const int hq  = tid >> 7;            // 0..3: h-quarter (wave-pair uniform)
    const int lane = tid & 63;

    // stage Ep = exp2(hp') rows + wc row into LDS (coalesced); mask
    for (int i = tid; i < PT * Hh; i += 512)
        ((float*)Eps)[i] = __builtin_amdgcn_exp2f(hp_all[(size_t)bp0 * Hh + i]);
    for (int i = tid; i < Hh; i += 512)      wc_s[i] = Wout[(size_t)c * Hh + i];
    if (tid < PT * Ss) {
        const int p_i = tid >> 7;
        const int aa  = tid & (Ss - 1);
        int any = 0;
        if (att[b * Ss + aa] > 0) {
            const int* ngp = ng + (size_t)(bp0 + p_i) * Cc * Ss + aa;
            #pragma unroll
            for (int cc = 0; cc < Cc; ++cc) any |= ngp[cc * Ss];
        }
        maskneg[p_i][aa] = any ? 0.0f : NEGV;
    }
    __syncthreads();

    if (tid < 64) {    // wave 0: sumW[c]
        float s = 0.f;
        #pragma unroll
        for (int i = 0; i < Hh / 64; ++i) s += wc_s[tid + i * 64];
        #pragma unroll
        for (int off = 32; off; off >>= 1) s += __shfl_xor(s, off, 64);
        if (tid == 0) swr_s = s;
    }

    // thread's ha stream: uint4 j (8 h each); index = (hq*24 + j)*128 + a
    const uint4* hap4 = (const uint4*)(haTb + ((size_t)(b * Cc + c) * 96) * 1024)
                      + (size_t)hq * 24 * 128 + a;
    const int hbase = hq * 192;

    uint4 A0, A1, A2, A3;
    uint4 B0, B1, B2, B3;
    float ac00 = 0.f, ac01 = 0.f, ac10 = 0.f, ac11 = 0.f;

    LOADG4(A, 0) SB
    LOADG4(B, 1) SB  CONSUMEG4(A, 0) SB
    LOADG4(A, 2) SB  CONSUMEG4(B, 1) SB
    LOADG4(B, 3) SB  CONSUMEG4(A, 2) SB
    LOADG4(A, 4) SB  CONSUMEG4(B, 3) SB
    LOADG4(B, 5) SB  CONSUMEG4(A, 4) SB
    CONSUMEG4(B, 5)

    if (hq != 0) {
        partial[0][hq - 1][a] = ac00 + ac01;
        partial[1][hq - 1][a] = ac10 + ac11;
    }
    __syncthreads();

    float logit[PT];
    const int wv = tid >> 6;             // 0/1 for hq==0 threads
    if (hq == 0) {
        const float ps[PT] = { ac00 + ac01, ac10 + ac11 };
        #pragma unroll
        for (int p = 0; p < PT; ++p) {
            const float full = ps[p] + partial[p][0][a] + partial[p][1][a] + partial[p][2][a];
            logit[p] = swr_s - 2.0f * full + maskneg[p][a];
            out_logits[((size_t)(bp0 + p) * Cc + c) * Ss + a] = logit[p];
            float mx = logit[p];
            #pragma unroll
            for (int off = 32; off; off >>= 1) mx = fmaxf(mx, __shfl_xor(mx, off, 64));
            if (lane == 0) redmax[p][wv] = mx;
        }
    }
    __syncthreads();

    if (hq == 0) {
        #pragma unroll
        for (int p = 0; p < PT; ++p) {
            const float rm = fmaxf(redmax[p][0], redmax[p][1]);
            const float e  = __builtin_amdgcn_exp2f((logit[p] - rm) * 1.4426950408889634f);
            const float tg = target[((size_t)(bp0 + p) * Cc + c) * Ss + a];
            float se = e, st = tg, sx = tg * logit[p];
            #pragma unroll
            for (int off = 32; off; off >>= 1) {
                se += __shfl_xor(se, off, 64);
                st += __shfl_xor(st, off, 64);
                sx += __shfl_xor(sx, off, 64);
            }
            if (lane == 0) { red3[p][wv][0] = se; red3[p][wv][1] = st; red3[p][wv][2] = sx; }
        }
    }
    __syncthreads();

    if (tid == 0) {
        float nsum = 0.f, dsum = 0.f;
        #pragma unroll
        for (int p = 0; p < PT; ++p) {
            const float rm = fmaxf(redmax[p][0], redmax[p][1]);
            const float SE = red3[p][0][0] + red3[p][1][0];
            const float ST = red3[p][0][1] + red3[p][1][1];
            const float SX = red3[p][0][2] + red3[p][1][2];
            const float lse = rm + __builtin_amdgcn_logf(SE) * 0.6931471805599453f;
            nsum += lse * ST - SX;
            dsum += ST;
        }
        atomicAdd(&accum[0], nsum);
        atomicAdd(&accum[1], dsum);
        __threadfence();
        const unsigned old = atomicAdd((unsigned*)(accum + 2), 1u);
        if (old == (unsigned)(NBLK - 1)) {          // last block: finalize loss
            const float n = atomicAdd(&accum[0], 0.0f);
            const float d = atomicAdd(&accum[1], 0.0f);
            out_loss[0] = n / d;
        }
    }
}

extern "C" void kernel_launch(void* const* d_in, const int* in_sizes, int n_in,
                              void* d_out, int out_size, void* d_ws, size_t ws_size,
                              hipStream_t stream) {
    const float* seq    = (const float*)d_in[0];
    const int*   att    = (const int*)  d_in[1];
    const int*   ng     = (const int*)  d_in[2];
    const float* target = (const float*)d_in[3];
    const float* Wprd   = (const float*)d_in[4];
    const float* bprd   = (const float*)d_in[5];
    const float* Warg   = (const float*)d_in[6];
    const float* barg   = (const float*)d_in[7];
    const float* Wout   = (const float*)d_in[8];

    float*  out    = (float*)d_out;
    float*  hp_out = (float*)d_ws;                       // 196608 floats
    ushort* haTb   = (ushort*)(hp_out + 196608);         // 983040 ushorts
    float*  accum  = hp_out + 196608 + 491520;           // 3 slots

    gemm_mfma<<<dim3(4, 144), 256, 0, stream>>>(seq, Wprd, Warg, bprd, barg,
                                                hp_out, haTb, accum);
    biaffine_loss<<<dim3(NBLK), 512, 0, stream>>>(hp_out, haTb, Wout, ng, att, target,
                                                  out + 1, accum, out);
}

// Round 18
// 132.093 us; speedup vs baseline: 2.0854x; 1.0156x over previous
//
#include <hip/hip_runtime.h>
#include <math.h>

#define Bb 2
#define Ss 128
#define Hh 768
#define Cc 5
#define Mm 256       // Bb*Ss
#define NEGV -1024.0f
#define SCALE 2.8853900817779268f   // 2/ln(2): Ep*Ea = e^{2x}

// haTb: bf16 [b][c][h8][a][h&7], h8=h>>3 in [0,96)
#define PT 2
#define NBLK (Mm / PT * Cc)   // 640

typedef __attribute__((ext_vector_type(8))) short bf16x8;
typedef __attribute__((ext_vector_type(4))) float f32x4;
typedef unsigned short ushort;

__device__ __forceinline__ unsigned pack_hi16(float hi, float lo) {
    return (__float_as_uint(hi) & 0xFFFF0000u) | (__float_as_uint(lo) >> 16);
}
__device__ __forceinline__ bf16x8 pack_bf16x8(float4 lo, float4 hi) {
    union { bf16x8 v; unsigned u[4]; } r;
    r.u[0] = pack_hi16(lo.y, lo.x);
    r.u[1] = pack_hi16(lo.w, lo.z);
    r.u[2] = pack_hi16(hi.y, hi.x);
    r.u[3] = pack_hi16(hi.w, hi.z);
    return r.v;
}

#define SB __builtin_amdgcn_sched_barrier(0);

// ---------------- Kernel 1: LDS-staged bf16 MFMA GEMM; hp branch stores Ep=exp2(hp') ----------------
__global__ __launch_bounds__(256)
void gemm_mfma(const float* __restrict__ X,
               const float* __restrict__ Wprd,
               const float* __restrict__ Warg,
               const float* __restrict__ bprd,
               const float* __restrict__ barg,
               float* __restrict__ EpG,
               ushort* __restrict__ haTb,
               float* __restrict__ accum)
{
    __shared__ __align__(16) ushort Asb[64][40];
    __shared__ __align__(16) ushort Bsb[32][40];

    if (blockIdx.x == 0 && blockIdx.y == 0 && threadIdx.x == 0) {
        accum[0] = 0.f; accum[1] = 0.f;
        ((unsigned*)accum)[2] = 0u;      // completion counter
    }
    const int bm   = blockIdx.x;          // 0..3   (64 rows)
    const int bn   = blockIdx.y;          // 0..143 (32 cols)
    const int tid  = threadIdx.x;
    const int wave = tid >> 6;
    const int lane = tid & 63;
    const int l16  = lane & 15;
    const int quad = lane >> 4;

    const float* Wsrc; const float* bsrc;
    const int nb = bn * 32;
    if (nb < Hh) { Wsrc = Wprd + (size_t)nb * Hh;        bsrc = bprd + nb; }
    else         { Wsrc = Warg + (size_t)(nb - Hh) * Hh; bsrc = barg + (nb - Hh); }

    const int srow = tid >> 2;
    const int sko  = (tid & 3) * 8;
    const float* gA = X + (size_t)(bm * 64 + srow) * Hh + sko;
    const float* gB = Wsrc + (size_t)(tid >> 2) * Hh + sko;   // valid for tid<128

    float4 pa0 = *(const float4*)(gA);
    float4 pa1 = *(const float4*)(gA + 4);
    float4 pb0, pb1;
    if (tid < 128) { pb0 = *(const float4*)(gB); pb1 = *(const float4*)(gB + 4); }

    f32x4 acc0 = {0.f,0.f,0.f,0.f}, acc1 = {0.f,0.f,0.f,0.f};

    for (int k0 = 0; k0 < Hh; k0 += 32) {
        *(bf16x8*)&Asb[srow][sko] = pack_bf16x8(pa0, pa1);
        if (tid < 128) *(bf16x8*)&Bsb[tid >> 2][sko] = pack_bf16x8(pb0, pb1);
        __syncthreads();
        const int kn = k0 + 32;
        if (kn < Hh) {
            pa0 = *(const float4*)(gA + kn);
            pa1 = *(const float4*)(gA + kn + 4);
            if (tid < 128) { pb0 = *(const float4*)(gB + kn); pb1 = *(const float4*)(gB + kn + 4); }
        }
        bf16x8 af = *(const bf16x8*)&Asb[wave * 16 + l16][quad * 8];
        bf16x8 b0 = *(const bf16x8*)&Bsb[l16][quad * 8];
        bf16x8 b1 = *(const bf16x8*)&Bsb[16 + l16][quad * 8];
        acc0 = __builtin_amdgcn_mfma_f32_16x16x32_bf16(af, b0, acc0, 0, 0, 0);
        acc1 = __builtin_amdgcn_mfma_f32_16x16x32_bf16(af, b1, acc1, 0, 0, 0);
        __syncthreads();
    }

    const float sb0 = SCALE * bsrc[l16];
    const float sb1 = SCALE * bsrc[16 + l16];
    const int row = bm * 64 + wave * 16 + quad * 4;

    if (nb < Hh) {   // Ep: row-major fp32 [m][h] = exp2(hp')
        #pragma unroll
        for (int r = 0; r < 4; ++r) {
            const int mm = row + r;
            EpG[(size_t)mm * Hh + nb + l16]      = __builtin_amdgcn_exp2f(SCALE * acc0[r] + sb0);
            EpG[(size_t)mm * Hh + nb + 16 + l16] = __builtin_amdgcn_exp2f(SCALE * acc1[r] + sb1);
        }
    } else {         // ha -> haTb bf16 [b][c][h>>3][a][h&7]
        const int q  = nb - Hh;
        const int cU = q / Hh;
        const int h0 = q % Hh;
        const int hA = h0 + l16;
        const int hB = h0 + 16 + l16;
        const size_t offA = (size_t)(hA >> 3) * 1024 + (hA & 7);
        const size_t offB = (size_t)(hB >> 3) * 1024 + (hB & 7);
        #pragma unroll
        for (int r = 0; r < 4; ++r) {
            const int mm = row + r;
            const int bI = mm >> 7, aI = mm & 127;
            const size_t base = ((size_t)(bI * Cc + cU) * 96) * 1024 + (size_t)aI * 8;
            const float v0 = SCALE * acc0[r] + sb0;
            const float v1 = SCALE * acc1[r] + sb1;
            haTb[base + offA] = (ushort)(__float_as_uint(v0) >> 16);
            haTb[base + offB] = (ushort)(__float_as_uint(v1) >> 16);
        }
    }
}

// ---------------- Kernel 2: biaffine; w/Ep via scalar (SMEM) loads, no big LDS arrays ----------------
// Grid 640 = (p-tile, c), 512 thr: tid = hq*128 + a. term = w * rcp(Ep*Ea + 1), Ea shared over p.
#define LOADG4(R, g) \
    R##0 = hap4[((g)*4+0)*128]; R##1 = hap4[((g)*4+1)*128]; \
    R##2 = hap4[((g)*4+2)*128]; R##3 = hap4[((g)*4+3)*128];

#define C1(u, hx) { \
    float w8[8], q0[8], q1[8]; \
    _Pragma("unroll") \
    for (int z = 0; z < 8; ++z) { \
        w8[z] = wrow[(hx) + z]; q0[z] = ep0[(hx) + z]; q1[z] = ep1[(hx) + z]; \
    } \
    const float e0 = __builtin_amdgcn_exp2f(__uint_as_float((u).x << 16)); \
    const float e1 = __builtin_amdgcn_exp2f(__uint_as_float((u).x & 0xFFFF0000u)); \
    const float e2 = __builtin_amdgcn_exp2f(__uint_as_float((u).y << 16)); \
    const float e3 = __builtin_amdgcn_exp2f(__uint_as_float((u).y & 0xFFFF0000u)); \
    const float e4 = __builtin_amdgcn_exp2f(__uint_as_float((u).z << 16)); \
    const float e5 = __builtin_amdgcn_exp2f(__uint_as_float((u).z & 0xFFFF0000u)); \
    const float e6 = __builtin_amdgcn_exp2f(__uint_as_float((u).w << 16)); \
    const float e7 = __builtin_amdgcn_exp2f(__uint_as_float((u).w & 0xFFFF0000u)); \
    float r; \
    r = __builtin_amdgcn_rcpf(fmaf(q0[0], e0, 1.0f)); ac00 = fmaf(w8[0], r, ac00); \
    r = __builtin_amdgcn_rcpf(fmaf(q0[1], e1, 1.0f)); ac01 = fmaf(w8[1], r, ac01); \
    r = __builtin_amdgcn_rcpf(fmaf(q0[2], e2, 1.0f)); ac00 = fmaf(w8[2], r, ac00); \
    r = __builtin_amdgcn_rcpf(fmaf(q0[3], e3, 1.0f)); ac01 = fmaf(w8[3], r, ac01); \
    r = __builtin_amdgcn_rcpf(fmaf(q0[4], e4, 1.0f)); ac00 = fmaf(w8[4], r, ac00); \
    r = __builtin_amdgcn_rcpf(fmaf(q0[5], e5, 1.0f)); ac01 = fmaf(w8[5], r, ac01); \
    r = __builtin_amdgcn_rcpf(fmaf(q0[6], e6, 1.0f)); ac00 = fmaf(w8[6], r, ac00); \
    r = __builtin_amdgcn_rcpf(fmaf(q0[7], e7, 1.0f)); ac01 = fmaf(w8[7], r, ac01); \
    r = __builtin_amdgcn_rcpf(fmaf(q1[0], e0, 1.0f)); ac10 = fmaf(w8[0], r, ac10); \
    r = __builtin_amdgcn_rcpf(fmaf(q1[1], e1, 1.0f)); ac11 = fmaf(w8[1], r, ac11); \
    r = __builtin_amdgcn_rcpf(fmaf(q1[2], e2, 1.0f)); ac10 = fmaf(w8[2], r, ac10); \
    r = __builtin_amdgcn_rcpf(fmaf(q1[3], e3, 1.0f)); ac11 = fmaf(w8[3], r, ac11); \
    r = __builtin_amdgcn_rcpf(fmaf(q1[4], e4, 1.0f)); ac10 = fmaf(w8[4], r, ac10); \
    r = __builtin_amdgcn_rcpf(fmaf(q1[5], e5, 1.0f)); ac11 = fmaf(w8[5], r, ac11); \
    r = __builtin_amdgcn_rcpf(fmaf(q1[6], e6, 1.0f)); ac10 = fmaf(w8[6], r, ac10); \
    r = __builtin_amdgcn_rcpf(fmaf(q1[7], e7, 1.0f)); ac11 = fmaf(w8[7], r, ac11); \
}

#define CONSUMEG4(R, g) \
    C1(R##0, hbase + ((g)*4+0)*8)  C1(R##1, hbase + ((g)*4+1)*8) \
    C1(R##2, hbase + ((g)*4+2)*8)  C1(R##3, hbase + ((g)*4+3)*8)

__global__ __launch_bounds__(512, 6)
void biaffine_loss(const float* __restrict__ EpG,
                   const ushort* __restrict__ haTb,
                   const float* __restrict__ Wout,
                   const int* __restrict__ ng,
                   const int* __restrict__ att,
                   const float* __restrict__ target,
                   float* __restrict__ out_logits,
                   float* __restrict__ accum,
                   float* __restrict__ out_loss)
{
    __shared__ float partial[PT][3][Ss];
    __shared__ float maskneg[PT][Ss];
    __shared__ float redmax[PT][2];
    __shared__ float red3[PT][2][3];
    __shared__ float swr_s;

    const int pt  = blockIdx.x / Cc;     // 0..127
    const int c   = blockIdx.x - pt * Cc;
    const int bp0 = pt * PT;
    const int b   = bp0 >> 7;
    const int tid = threadIdx.x;
    const int a   = tid & (Ss - 1);
    const int hq  = __builtin_amdgcn_readfirstlane(tid >> 7);   // 0..3, forced SGPR
    const int lane = tid & 63;

    // uniform base pointers for scalar loads
    const float* wrow = Wout + (size_t)c * Hh;
    const float* ep0  = EpG + (size_t)(bp0 + 0) * Hh;
    const float* ep1  = EpG + (size_t)(bp0 + 1) * Hh;

    if (tid < PT * Ss) {   // mask staging
        const int p_i = tid >> 7;
        const int aa  = tid & (Ss - 1);
        int any = 0;
        if (att[b * Ss + aa] > 0) {
            const int* ngp = ng + (size_t)(bp0 + p_i) * Cc * Ss + aa;
            #pragma unroll
            for (int cc = 0; cc < Cc; ++cc) any |= ngp[cc * Ss];
        }
        maskneg[p_i][aa] = any ? 0.0f : NEGV;
    }

    if (tid < 64) {    // wave 0: sumW[c] from global (coalesced)
        float s = 0.f;
        #pragma unroll
        for (int i = 0; i < Hh / 64; ++i) s += wrow[tid + i * 64];
        #pragma unroll
        for (int off = 32; off; off >>= 1) s += __shfl_xor(s, off, 64);
        if (tid == 0) swr_s = s;
    }

    // thread's ha stream: uint4 j (8 h each); index = (hq*24 + j)*128 + a
    const uint4* hap4 = (const uint4*)(haTb + ((size_t)(b * Cc + c) * 96) * 1024)
                      + (size_t)hq * 24 * 128 + a;
    const int hbase = hq * 192;

    uint4 A0, A1, A2, A3;
    uint4 B0, B1, B2, B3;
    float ac00 = 0.f, ac01 = 0.f, ac10 = 0.f, ac11 = 0.f;

    LOADG4(A, 0) SB
    LOADG4(B, 1) SB  CONSUMEG4(A, 0) SB
    LOADG4(A, 2) SB  CONSUMEG4(B, 1) SB
    LOADG4(B, 3) SB  CONSUMEG4(A, 2) SB
    LOADG4(A, 4) SB  CONSUMEG4(B, 3) SB
    LOADG4(B, 5) SB  CONSUMEG4(A, 4) SB
    CONSUMEG4(B, 5)

    if (hq != 0) {
        partial[0][hq - 1][a] = ac00 + ac01;
        partial[1][hq - 1][a] = ac10 + ac11;
    }
    __syncthreads();

    float logit[PT];
    const int wv = tid >> 6;             // 0/1 for hq==0 threads
    if (hq == 0) {
        const float ps[PT] = { ac00 + ac01, ac10 + ac11 };
        #pragma unroll
        for (int p = 0; p < PT; ++p) {
            const float full = ps[p] + partial[p][0][a] + partial[p][1][a] + partial[p][2][a];
            logit[p] = swr_s - 2.0f * full + maskneg[p][a];
            out_logits[((size_t)(bp0 + p) * Cc + c) * Ss + a] = logit[p];
            float mx = logit[p];
            #pragma unroll
            for (int off = 32; off; off >>= 1) mx = fmaxf(mx, __shfl_xor(mx, off, 64));
            if (lane == 0) redmax[p][wv] = mx;
        }
    }
    __syncthreads();

    if (hq == 0) {
        #pragma unroll
        for (int p = 0; p < PT; ++p) {
            const float rm = fmaxf(redmax[p][0], redmax[p][1]);
            const float e  = __builtin_amdgcn_exp2f((logit[p] - rm) * 1.4426950408889634f);
            const float tg = target[((size_t)(bp0 + p) * Cc + c) * Ss + a];
            float se = e, st = tg, sx = tg * logit[p];
            #pragma unroll
            for (int off = 32; off; off >>= 1) {
                se += __shfl_xor(se, off, 64);
                st += __shfl_xor(st, off, 64);
                sx += __shfl_xor(sx, off, 64);
            }
            if (lane == 0) { red3[p][wv][0] = se; red3[p][wv][1] = st; red3[p][wv][2] = sx; }
        }
    }
    __syncthreads();

    if (tid == 0) {
        float nsum = 0.f, dsum = 0.f;
        #pragma unroll
        for (int p = 0; p < PT; ++p) {
            const float rm = fmaxf(redmax[p][0], redmax[p][1]);
            const float SE = red3[p][0][0] + red3[p][1][0];
            const float ST = red3[p][0][1] + red3[p][1][1];
            const float SX = red3[p][0][2] + red3[p][1][2];
            const float lse = rm + __builtin_amdgcn_logf(SE) * 0.6931471805599453f;
            nsum += lse * ST - SX;
            dsum += ST;
        }
        atomicAdd(&accum[0], nsum);
        atomicAdd(&accum[1], dsum);
        __threadfence();
        const unsigned old = atomicAdd((unsigned*)(accum + 2), 1u);
        if (old == (unsigned)(NBLK - 1)) {          // last block: finalize loss
            const float n = atomicAdd(&accum[0], 0.0f);
            const float d = atomicAdd(&accum[1], 0.0f);
            out_loss[0] = n / d;
        }
    }
}

extern "C" void kernel_launch(void* const* d_in, const int* in_sizes, int n_in,
                              void* d_out, int out_size, void* d_ws, size_t ws_size,
                              hipStream_t stream) {
    const float* seq    = (const float*)d_in[0];
    const int*   att    = (const int*)  d_in[1];
    const int*   ng     = (const int*)  d_in[2];
    const float* target = (const float*)d_in[3];
    const float* Wprd   = (const float*)d_in[4];
    const float* bprd   = (const float*)d_in[5];
    const float* Warg   = (const float*)d_in[6];
    const float* barg   = (const float*)d_in[7];
    const float* Wout   = (const float*)d_in[8];

    float*  out    = (float*)d_out;
    float*  EpG    = (float*)d_ws;                       // 196608 floats
    ushort* haTb   = (ushort*)(EpG + 196608);            // 983040 ushorts
    float*  accum  = EpG + 196608 + 491520;              // 3 slots

    gemm_mfma<<<dim3(4, 144), 256, 0, stream>>>(seq, Wprd, Warg, bprd, barg,
                                                EpG, haTb, accum);
    biaffine_loss<<<dim3(NBLK), 512, 0, stream>>>(EpG, haTb, Wout, ng, att, target,
                                                  out + 1, accum, out);
}